// Round 1
// baseline (36.246 us; speedup 1.0000x reference)
//
#include <hip/hip_runtime.h>

#define NB   4096   // tokens
#define NE   32     // experts
#define DIN  256
#define DOUT 256
#define TM   32     // tokens per tile
#define TN   128    // outputs per tile (DOUT/2)

// ws layout (int units):
//   [0]              ntiles
//   [8 .. 8+2*160)   tile descriptors (expert, token_start) pairs
//   [1024 .. 1057)   offsets[33] (exclusive scan of counts)
//   [2048 .. 6144)   sorted token ids
#define WS_DESC   8
#define WS_OFFS   1024
#define WS_SORT   2048

__global__ __launch_bounds__(1024) void sort_kernel(const int* __restrict__ idx,
                                                    int* __restrict__ ws) {
    __shared__ int cnt[NE];
    __shared__ int pos[NE];
    __shared__ int offs[NE + 1];
    const int tid = threadIdx.x;
    if (tid < NE) { cnt[tid] = 0; pos[tid] = 0; }
    __syncthreads();

    // 4096 tokens / 1024 threads = 4 each, int4 coalesced
    const int i0 = tid * 4;
    const int4 v = *reinterpret_cast<const int4*>(idx + i0);
    atomicAdd(&cnt[v.x], 1);
    atomicAdd(&cnt[v.y], 1);
    atomicAdd(&cnt[v.z], 1);
    atomicAdd(&cnt[v.w], 1);
    __syncthreads();

    if (tid == 0) {
        int run = 0, nt = 0;
        for (int e = 0; e < NE; ++e) {
            offs[e] = run;
            const int c = cnt[e];
            for (int t = 0; t < c; t += TM) {
                ws[WS_DESC + 2 * nt]     = e;
                ws[WS_DESC + 2 * nt + 1] = run + t;
                ++nt;
            }
            run += c;
        }
        offs[NE] = run;
        ws[0] = nt;
    }
    __syncthreads();

    if (tid <= NE) ws[WS_OFFS + tid] = offs[tid];

    int* sorted = ws + WS_SORT;
    int r;
    r = atomicAdd(&pos[v.x], 1); sorted[offs[v.x] + r] = i0 + 0;
    r = atomicAdd(&pos[v.y], 1); sorted[offs[v.y] + r] = i0 + 1;
    r = atomicAdd(&pos[v.z], 1); sorted[offs[v.z] + r] = i0 + 2;
    r = atomicAdd(&pos[v.w], 1); sorted[offs[v.w] + r] = i0 + 3;
}

__global__ __launch_bounds__(256) void gemm_kernel(const float* __restrict__ x,
                                                   const float* __restrict__ w,
                                                   const float* __restrict__ bias,
                                                   const int* __restrict__ ws,
                                                   float* __restrict__ out) {
    const int ntiles = ws[0];
    const int tile = blockIdx.x;
    if (tile >= ntiles) return;

    const int e     = ws[WS_DESC + 2 * tile];
    const int start = ws[WS_DESC + 2 * tile + 1];
    const int ende  = ws[WS_OFFS + e + 1];
    const int m     = min(TM, ende - start);
    const int* __restrict__ sorted = ws + WS_SORT;
    const int obase = blockIdx.y * TN;

    __shared__ float xs[DIN][TM];   // 32 KB, [k][token]

    const int tid = threadIdx.x;

    // ---- stage x tile (transposed) into LDS ----
    {
        const int t = tid & 31;        // token slot
        const int g = tid >> 5;        // 0..7 k-groups
        const int trow = sorted[start + min(t, m - 1)];
        const float* xrow = x + (size_t)trow * DIN;
#pragma unroll
        for (int j = 0; j < 8; ++j) {
            const int k0 = (g * 8 + j) * 4;
            const float4 vv = *reinterpret_cast<const float4*>(xrow + k0);
            xs[k0 + 0][t] = vv.x;
            xs[k0 + 1][t] = vv.y;
            xs[k0 + 2][t] = vv.z;
            xs[k0 + 3][t] = vv.w;
        }
    }
    __syncthreads();

    // ---- main loop: thread tile 4 tokens x 4 outputs ----
    const int og = tid & 31;   // output group: 32 x 4 = 128 outs
    const int tg = tid >> 5;   // token group:   8 x 4 =  32 tokens
    const float* wp = w + (size_t)e * DIN * DOUT + obase + og * 4;

    float acc[4][4] = {};   // [token][out]
#pragma unroll 8
    for (int k = 0; k < DIN; ++k) {
        const float4 wv = *reinterpret_cast<const float4*>(wp + (size_t)k * DOUT);
        const float4 xv = *reinterpret_cast<const float4*>(&xs[k][tg * 4]);
        const float xr[4] = {xv.x, xv.y, xv.z, xv.w};
        const float wr[4] = {wv.x, wv.y, wv.z, wv.w};
#pragma unroll
        for (int a = 0; a < 4; ++a)
#pragma unroll
            for (int b = 0; b < 4; ++b)
                acc[a][b] = fmaf(xr[a], wr[b], acc[a][b]);
    }

    // ---- epilogue: add bias, scatter to out rows ----
    const float4 bv = *reinterpret_cast<const float4*>(bias + (size_t)e * DOUT + obase + og * 4);
#pragma unroll
    for (int tt = 0; tt < 4; ++tt) {
        const int tl = tg * 4 + tt;
        if (tl < m) {
            const int row = sorted[start + tl];
            float4 o;
            o.x = acc[tt][0] + bv.x;
            o.y = acc[tt][1] + bv.y;
            o.z = acc[tt][2] + bv.z;
            o.w = acc[tt][3] + bv.w;
            *reinterpret_cast<float4*>(out + (size_t)row * DOUT + obase + og * 4) = o;
        }
    }
}

extern "C" void kernel_launch(void* const* d_in, const int* in_sizes, int n_in,
                              void* d_out, int out_size, void* d_ws, size_t ws_size,
                              hipStream_t stream) {
    const float* x      = (const float*)d_in[0];
    const int*   index  = (const int*)d_in[1];
    const float* weight = (const float*)d_in[2];
    const float* bias   = (const float*)d_in[3];
    float* out = (float*)d_out;
    int* ws = (int*)d_ws;

    sort_kernel<<<1, 1024, 0, stream>>>(index, ws);

    // worst-case tiles: 128 full + up to 31 partial = 159
    dim3 grid(160, 2);
    gemm_kernel<<<grid, 256, 0, stream>>>(x, weight, bias, ws, out);
}